// Round 19
// baseline (20781.599 us; speedup 1.0000x reference)
//
#include <hip/hip_runtime.h>
#include <math.h>

#define B 256
#define T 512
#define H 1024
#define NBLK 128

typedef _Float16 f16x8 __attribute__((ext_vector_type(8)));
typedef float f32x4 __attribute__((ext_vector_type(4)));
typedef unsigned u32x4 __attribute__((ext_vector_type(4)));

__device__ __forceinline__ float sigmoidf_(float x) { return 1.0f / (1.0f + __expf(-x)); }
__device__ __forceinline__ float tanhf_(float x) {
    float ax = fabsf(x);
    float t = __expf(-2.0f * ax);
    float r = (1.0f - t) / (1.0f + t);
    return x < 0.f ? -r : r;
}

// ---- agent-coherent access (write-through LLC, bypass L1/L2; no fences) ----
__device__ __forceinline__ void store_b128_coh(void* p, u32x4 v) {
    asm volatile("global_store_dwordx4 %0, %1, off sc0 sc1" :: "v"(p), "v"(v) : "memory");
}
__device__ __forceinline__ u32x4 load_b16_coh(const void* p) {
    u32x4 v;
    asm volatile("global_load_dwordx4 %0, %1, off sc0 sc1" : "=v"(v) : "v"(p));
    return v;
}
__device__ __forceinline__ void storef_coh(float* p, float v) {
    __hip_atomic_store(p, v, __ATOMIC_RELAXED, __HIP_MEMORY_SCOPE_AGENT);
}
__device__ __forceinline__ float loadf_coh(const float* p) {
    return __hip_atomic_load((float*)p, __ATOMIC_RELAXED, __HIP_MEMORY_SCOPE_AGENT);
}

// Load this wave's 48 B-fragments (3 gates x 16 k-chunks of its K-half),
// f32 -> f16. j = this lane's B row; one-time cost (lives in AGPRs).
__device__ __forceinline__ void load_weights(f16x8 (&wB)[48], const float* __restrict__ W,
                                             int j, int kh, int kg) {
#pragma unroll
    for (int g = 0; g < 3; ++g)
#pragma unroll
        for (int i = 0; i < 16; ++i) {
            const float* p = W + (((size_t)g << 10) + j) * 1024 + (kh << 9) + (i << 5) + (kg << 3);
            float4 u = *(const float4*)p;
            float4 v = *(const float4*)(p + 4);
            f16x8 o;
            o[0] = (_Float16)u.x; o[1] = (_Float16)u.y; o[2] = (_Float16)u.z; o[3] = (_Float16)u.w;
            o[4] = (_Float16)v.x; o[5] = (_Float16)v.y; o[6] = (_Float16)v.z; o[7] = (_Float16)v.w;
            wB[g * 16 + i] = o;
        }
}

// ---- publish + sync tail (R9 protocol, 8-block group, 128-col slice) ----
// wave0: 256 coalesced 16B write-through stores of hout -> hn slice (4/lane),
//        vmcnt(0) drain, tid0 stores tag = gcur+1.
// wave2 lanes 0..7: poll all 8 group tags >= gcur+1 (overlaps wave0 drain).
// __syncthreads joins. Monotone tags, no reset race.
#define PUBLISH_SYNC(hn_expr, EXTRA_STORES)                                              \
    do {                                                                                 \
        if (tid < 64) {                                                                  \
            _Float16* hn_ = (hn_expr);                                                   \
            _Pragma("unroll")                                                            \
            for (int pi = 0; pi < 4; ++pi) {                                             \
                int c = tid + 64 * pi;                                                   \
                int prow = c >> 4, pch = c & 15;                                         \
                store_b128_coh(hn_ + ((size_t)(b0 + prow) << 10) + j0 + pch * 8,         \
                               *(const u32x4*)&hout[prow][pch * 8]);                     \
            }                                                                            \
        }                                                                                \
        EXTRA_STORES                                                                     \
        if (tid >= 128 && tid < 136) {                                                   \
            unsigned tgt = gcur + 1;                                                     \
            while (__hip_atomic_load(&tags[(bt * 8 + (tid - 128)) * 32],                 \
                                     __ATOMIC_RELAXED, __HIP_MEMORY_SCOPE_AGENT) < tgt)  \
                __builtin_amdgcn_s_sleep(1);                                             \
        }                                                                                \
        if (tid < 64) {                                                                  \
            asm volatile("s_waitcnt vmcnt(0)" ::: "memory");                             \
            if (tid == 0)                                                                \
                __hip_atomic_store(&tags[(bt * 8 + jt) * 32], gcur + 1,                  \
                                   __ATOMIC_RELAXED, __HIP_MEMORY_SCOPE_AGENT);          \
        }                                                                                \
        __syncthreads();                                                                 \
        ++gcur;                                                                          \
    } while (0)

// One GRU phase: T steps. Weights in wB (AGPRs), h f32 master in hreg.
// h16 full-matrix [B][H] ping-pong: step t reads buf[t&1], writes buf[(t+1)&1].
template <bool DEC>
__device__ __forceinline__ void run_phase(
    int b0, int j0, int bt, int jt, int j, int np, int kh, int kg, int r16,
    int tid, int lane,
    const f16x8 (&wB)[48], float (&hreg)[4],
    _Float16* __restrict__ h16A, _Float16* __restrict__ h16B,
    const float* __restrict__ Wih, const float* __restrict__ bih,
    const float* __restrict__ bhh,
    const float* __restrict__ input, const float* __restrict__ Wout, float bout_v,
    float* __restrict__ xpart, float* __restrict__ outp,
    unsigned* tags, unsigned& gcur,
    char* Als, f32x4 (*red)[3][64], _Float16 (*hout)[128], float* xv_s, float (*xnp)[16])
{
    const float wi_r = Wih[j], wi_z = Wih[H + j], wi_n = Wih[2 * H + j];
    const float bi_r = bih[j], bi_z = bih[H + j], bi_n = bih[2 * H + j];
    const float bh_r = bhh[j], bh_z = bhh[H + j], bh_n = bhh[2 * H + j];
    const float wo = DEC ? Wout[j] : 0.f;
    const int kc = tid & 127, rb = tid >> 7;   // rb 0..7; rows rb and rb+8

    for (int t = 0; t < T; ++t) {
        const _Float16* hp = (t & 1) ? h16B : h16A;
        _Float16* hn = (t & 1) ? h16A : h16B;

        // ---- stage loads (freshness guaranteed by previous step's poll) ----
        u32x4 tmp0 = load_b16_coh(hp + ((size_t)(b0 + rb) << 10) + (kc << 3));
        u32x4 tmp1 = load_b16_coh(hp + ((size_t)(b0 + rb + 8) << 10) + (kc << 3));
        float xg = 0.f;
        if (DEC && t > 0 && tid < 16) {
            const float* xp = xpart + ((t - 1) & 1) * 2048 + (size_t)(b0 + tid) * 8;
#pragma unroll
            for (int q = 0; q < 8; ++q) xg += loadf_coh(xp + q);
            xg += bout_v;
        }
        asm volatile("s_waitcnt vmcnt(0)" ::: "memory");
        __builtin_amdgcn_sched_barrier(0);
        if (DEC && tid < 16) {
            float xv = (t > 0) ? xg : 0.f;
            xv_s[tid] = xv;
            if (t > 0 && jt == 0) outp[(size_t)(b0 + tid) * T + (t - 1)] = xv;
        }
        *(u32x4*)(Als + rb * 2048 + ((kc << 4) ^ ((rb & 7) << 4))) = tmp0;
        *(u32x4*)(Als + (rb + 8) * 2048 + ((kc << 4) ^ ((rb & 7) << 4))) = tmp1;
        __syncthreads();

        // ---- MFMA: 3 gates x K-half ----
        f32x4 aR = {0.f, 0.f, 0.f, 0.f}, aZ = {0.f, 0.f, 0.f, 0.f}, aN = {0.f, 0.f, 0.f, 0.f};
#pragma unroll
        for (int i = 0; i < 16; ++i) {
            int kb = (kh << 10) + (i << 6) + (kg << 4);
            f16x8 a = *(const f16x8*)(Als + (r16 << 11) + (kb ^ ((r16 & 7) << 4)));
            aR = __builtin_amdgcn_mfma_f32_16x16x32_f16(a, wB[i], aR, 0, 0, 0);
            aZ = __builtin_amdgcn_mfma_f32_16x16x32_f16(a, wB[16 + i], aZ, 0, 0, 0);
            aN = __builtin_amdgcn_mfma_f32_16x16x32_f16(a, wB[32 + i], aN, 0, 0, 0);
        }
        if (kh == 1) {
            red[np][0][lane] = aR; red[np][1][lane] = aZ; red[np][2][lane] = aN;
        }
        __syncthreads();

        // ---- epilogue: K-reduce + GRU cell -> hout (LDS), xw -> xnp ----
        if (kh == 0) {
            f32x4 rR = red[np][0][lane], rZ = red[np][1][lane], rN = red[np][2][lane];
#pragma unroll
            for (int reg = 0; reg < 4; ++reg) {
                int row = kg * 4 + reg;
                int b = b0 + row;
                float xv = DEC ? xv_s[row] : input[(size_t)b * T + t];
                float r = sigmoidf_(xv * wi_r + bi_r + aR[reg] + rR[reg] + bh_r);
                float z = sigmoidf_(xv * wi_z + bi_z + aZ[reg] + rZ[reg] + bh_z);
                float n = tanhf_(xv * wi_n + bi_n + r * (aN[reg] + rN[reg] + bh_n));
                float hNew = (1.f - z) * n + z * hreg[reg];
                hreg[reg] = hNew;
                hout[row][np * 16 + r16] = (_Float16)hNew;
                if (DEC) {
                    float v = hNew * wo;
                    v += __shfl_xor(v, 1); v += __shfl_xor(v, 2);
                    v += __shfl_xor(v, 4); v += __shfl_xor(v, 8);
                    if (r16 == 0) xnp[np][row] = v;
                }
            }
        }
        __syncthreads();

        // ---- publish h_{t+1} (+ xpart), poll peers, join ----
        PUBLISH_SYNC(hn,
            if (DEC && tid < 16) {
                float s_ = xnp[0][tid] + xnp[1][tid] + xnp[2][tid] + xnp[3][tid] +
                           xnp[4][tid] + xnp[5][tid] + xnp[6][tid] + xnp[7][tid];
                storef_coh(xpart + (t & 1) * 2048 + (size_t)(b0 + tid) * 8 + jt, s_);
            }
        );
    }
}

__global__ __launch_bounds__(1024) void gru_persistent(
    const float* __restrict__ input, const float* __restrict__ h_init,
    const float* __restrict__ Wih_e, const float* __restrict__ Whh_e,
    const float* __restrict__ bih_e, const float* __restrict__ bhh_e,
    const float* __restrict__ Wenc, const float* __restrict__ benc,
    const float* __restrict__ Wdec, const float* __restrict__ bdec,
    const float* __restrict__ Wih_d, const float* __restrict__ Whh_d,
    const float* __restrict__ bih_d, const float* __restrict__ bhh_d,
    const float* __restrict__ Wout, const float* __restrict__ boutp,
    float* __restrict__ featOut, float* __restrict__ outp,
    _Float16* __restrict__ h16A, _Float16* __restrict__ h16B,
    float* __restrict__ xpart, float* __restrict__ fpart,
    unsigned* tags)
{
    __shared__ __align__(16) char Als[32768];
    __shared__ f32x4 red[8][3][64];
    __shared__ __align__(16) _Float16 hout[16][128];
    __shared__ float xv_s[16];
    __shared__ float xnp[8][16];
    __shared__ float fp_np[8][16][3];
    __shared__ float feats[16][3];

    const int tid = threadIdx.x;
    const int lane = tid & 63;
    const int wv = tid >> 6;     // 0..15
    const int kh = wv & 1;       // K-half
    const int np = wv >> 1;      // n-octant 0..7
    const int kg = lane >> 4;    // 0..3
    const int r16 = lane & 15;
    const int bid = blockIdx.x;
    const int bt = bid & 15, jt = bid >> 4;   // 16 bt-groups x 8 j-blocks
    const int b0 = bt * 16, j0 = jt * 128;
    const int j = j0 + np * 16 + r16;
    const float bout_v = boutp[0];
    unsigned gcur = 0;

    f16x8 wB[48];
    float hreg[4] = {0.f, 0.f, 0.f, 0.f};

    // ---- init: hreg + publish h_init slice to h16A (par0) ----
    if (kh == 0) {
#pragma unroll
        for (int reg = 0; reg < 4; ++reg) {
            int row = kg * 4 + reg;
            float v = h_init[((size_t)(b0 + row) << 10) + j];
            hreg[reg] = v;
            hout[row][np * 16 + r16] = (_Float16)v;
        }
    }
    __syncthreads();
    PUBLISH_SYNC(h16A, );
    load_weights(wB, Whh_e, j, kh, kg);

    // ---- encoder: 512 steps ----
    run_phase<false>(b0, j0, bt, jt, j, np, kh, kg, r16, tid, lane, wB, hreg,
                     h16A, h16B, Wih_e, bih_e, bhh_e, input, Wout, bout_v,
                     xpart, outp, tags, gcur, Als, red, hout, xv_s, xnp);

    // ---- bottleneck: features (8-way j reduction) + h0 ----
    {
        float we0 = Wenc[j], we1 = Wenc[H + j], we2 = Wenc[2 * H + j];
        if (kh == 0) {
#pragma unroll
            for (int reg = 0; reg < 4; ++reg) {
                float h = hreg[reg];
                float q0 = h * we0, q1 = h * we1, q2 = h * we2;
#pragma unroll
                for (int m = 1; m < 16; m <<= 1) {
                    q0 += __shfl_xor(q0, m);
                    q1 += __shfl_xor(q1, m);
                    q2 += __shfl_xor(q2, m);
                }
                if (r16 == 0) {
                    fp_np[np][kg * 4 + reg][0] = q0;
                    fp_np[np][kg * 4 + reg][1] = q1;
                    fp_np[np][kg * 4 + reg][2] = q2;
                }
            }
        }
        __syncthreads();
        if (tid < 48) {
            int bi = tid / 3, c = tid % 3;
            float s = 0.f;
#pragma unroll
            for (int q = 0; q < 8; ++q) s += fp_np[q][bi][c];
            storef_coh(fpart + (size_t)(b0 + bi) * 24 + jt * 3 + c, s);
        }
        // sync (no h publish needed)
        if (tid >= 128 && tid < 136) {
            unsigned tgt = gcur + 1;
            while (__hip_atomic_load(&tags[(bt * 8 + (tid - 128)) * 32],
                                     __ATOMIC_RELAXED, __HIP_MEMORY_SCOPE_AGENT) < tgt)
                __builtin_amdgcn_s_sleep(1);
        }
        if (tid < 64) {
            asm volatile("s_waitcnt vmcnt(0)" ::: "memory");
            if (tid == 0)
                __hip_atomic_store(&tags[(bt * 8 + jt) * 32], gcur + 1,
                                   __ATOMIC_RELAXED, __HIP_MEMORY_SCOPE_AGENT);
        }
        __syncthreads();
        ++gcur;

        if (tid < 48) {
            int bi = tid / 3, c = tid % 3;
            float s = 0.f;
            const float* fp = fpart + (size_t)(b0 + bi) * 24 + c;
#pragma unroll
            for (int q = 0; q < 8; ++q) s += loadf_coh(fp + q * 3);
            float f = sigmoidf_(s + benc[c]);
            feats[bi][c] = f;
            if (jt == 0) featOut[(b0 + bi) * 3 + c] = f;
        }
        __syncthreads();

        // h0 = feats @ Wdec.T + bdec -> hreg + publish to h16A (decoder par0)
        if (kh == 0) {
#pragma unroll
            for (int reg = 0; reg < 4; ++reg) {
                int row = kg * 4 + reg;
                float v = feats[row][0] * Wdec[j * 3 + 0] + feats[row][1] * Wdec[j * 3 + 1] +
                          feats[row][2] * Wdec[j * 3 + 2] + bdec[j];
                hreg[reg] = v;
                hout[row][np * 16 + r16] = (_Float16)v;
            }
        }
        __syncthreads();
        PUBLISH_SYNC(h16A, );
        load_weights(wB, Whh_d, j, kh, kg);
    }

    // ---- decoder: 512 steps ----
    run_phase<true>(b0, j0, bt, jt, j, np, kh, kg, r16, tid, lane, wB, hreg,
                    h16A, h16B, Wih_d, bih_d, bhh_d, input, Wout, bout_v,
                    xpart, outp, tags, gcur, Als, red, hout, xv_s, xnp);

    // ---- final output column: x from step 511 (xpart slot 1, polled) ----
    if (jt == 0 && tid < 16) {
        const float* xp = xpart + 2048 + (size_t)(b0 + tid) * 8;
        float s = 0.f;
#pragma unroll
        for (int q = 0; q < 8; ++q) s += loadf_coh(xp + q);
        outp[(size_t)(b0 + tid) * T + (T - 1)] = s + bout_v;
    }
}

__global__ __launch_bounds__(256) void loss_partial(
    const float* __restrict__ input, const float* __restrict__ outp,
    float* __restrict__ partial)
{
    int idx = blockIdx.x * blockDim.x + threadIdx.x;
    float s = 0.f;
    for (int i = idx; i < B * T; i += gridDim.x * blockDim.x) {
        float d = input[i] - outp[i];
        s += d * d;
    }
#pragma unroll
    for (int off = 32; off; off >>= 1) s += __shfl_down(s, off);
    __shared__ float ws[4];
    if ((threadIdx.x & 63) == 0) ws[threadIdx.x >> 6] = s;
    __syncthreads();
    if (threadIdx.x == 0) partial[blockIdx.x] = ws[0] + ws[1] + ws[2] + ws[3];
}

__global__ __launch_bounds__(256) void loss_final(
    const float* __restrict__ partial, float* __restrict__ loss)
{
    int tid = threadIdx.x;
    float s = partial[tid];
#pragma unroll
    for (int off = 32; off; off >>= 1) s += __shfl_down(s, off);
    __shared__ float ws[4];
    if ((tid & 63) == 0) ws[tid >> 6] = s;
    __syncthreads();
    if (tid == 0) loss[0] = (ws[0] + ws[1] + ws[2] + ws[3]) * (1.0f / (float)(B * T));
}

extern "C" void kernel_launch(void* const* d_in, const int* in_sizes, int n_in,
                              void* d_out, int out_size, void* d_ws, size_t ws_size,
                              hipStream_t stream) {
    const float* input = (const float*)d_in[0];
    const float* h_init = (const float*)d_in[1];
    const float* Wih_e = (const float*)d_in[2];
    const float* Whh_e = (const float*)d_in[3];
    const float* bih_e = (const float*)d_in[4];
    const float* bhh_e = (const float*)d_in[5];
    const float* Wenc  = (const float*)d_in[6];
    const float* benc  = (const float*)d_in[7];
    const float* Wdec  = (const float*)d_in[8];
    const float* bdec  = (const float*)d_in[9];
    const float* Wih_d = (const float*)d_in[10];
    const float* Whh_d = (const float*)d_in[11];
    const float* bih_d = (const float*)d_in[12];
    const float* bhh_d = (const float*)d_in[13];
    const float* Wout  = (const float*)d_in[14];
    const float* bout  = (const float*)d_in[15];
    (void)in_sizes; (void)n_in; (void)out_size; (void)ws_size;

    float* out = (float*)d_out;
    float* lossp = out;                    // [1]
    float* feat = out + 1;                 // [B*3]
    float* outp = out + 1 + B * 3;         // [B*T]

    // ---- workspace layout ----
    char* ws = (char*)d_ws;
    _Float16* h16A = (_Float16*)ws;                  ws += (size_t)B * H * 2;
    _Float16* h16B = (_Float16*)ws;                  ws += (size_t)B * H * 2;
    float* xpart = (float*)ws;                       ws += 2 * 2048 * 4;   // [2][256][8]
    float* fpart = (float*)ws;                       ws += (size_t)B * 24 * 4;
    float* partial = (float*)ws;                     ws += 256 * 4;
    ws = (char*)(((uintptr_t)ws + 127) & ~(uintptr_t)127);
    unsigned* tags = (unsigned*)ws;                  ws += 16 * 8 * 32 * 4;  // padded tag lines

    // tags must start at 0 every call (ws poisoned once, not restored)
    hipMemsetAsync(tags, 0, 16 * 8 * 32 * 4, stream);

    gru_persistent<<<dim3(NBLK), dim3(1024), 0, stream>>>(
        input, h_init, Wih_e, Whh_e, bih_e, bhh_e, Wenc, benc, Wdec, bdec,
        Wih_d, Whh_d, bih_d, bhh_d, Wout, bout,
        feat, outp, h16A, h16B, xpart, fpart, tags);

    loss_partial<<<256, 256, 0, stream>>>(input, outp, partial);
    loss_final<<<1, 256, 0, stream>>>(partial, lossp);
}

// Round 20
// 5753.943 us; speedup vs baseline: 3.6117x; 3.6117x over previous
//
#include <hip/hip_runtime.h>
#include <math.h>

#define B 256
#define T 512
#define H 1024
#define NBLK 256

typedef _Float16 f16x8 __attribute__((ext_vector_type(8)));
typedef float f32x4 __attribute__((ext_vector_type(4)));
typedef unsigned u32x4 __attribute__((ext_vector_type(4)));

__device__ __forceinline__ float sigmoidf_(float x) { return 1.0f / (1.0f + __expf(-x)); }
__device__ __forceinline__ float tanhf_(float x) {
    float ax = fabsf(x);
    float t = __expf(-2.0f * ax);
    float r = (1.0f - t) / (1.0f + t);
    return x < 0.f ? -r : r;
}

// ---- agent-coherent access (write-through LLC, bypass L1/L2; no fences) ----
__device__ __forceinline__ void store_b128_coh(void* p, u32x4 v) {
    asm volatile("global_store_dwordx4 %0, %1, off sc0 sc1" :: "v"(p), "v"(v) : "memory");
}
__device__ __forceinline__ u32x4 load_b16_coh(const void* p) {
    u32x4 v;
    asm volatile("global_load_dwordx4 %0, %1, off sc0 sc1" : "=v"(v) : "v"(p));
    return v;
}
__device__ __forceinline__ void storef_coh(float* p, float v) {
    __hip_atomic_store(p, v, __ATOMIC_RELAXED, __HIP_MEMORY_SCOPE_AGENT);
}
__device__ __forceinline__ float loadf_coh(const float* p) {
    return __hip_atomic_load((float*)p, __ATOMIC_RELAXED, __HIP_MEMORY_SCOPE_AGENT);
}

// Load this wave's 48 B-fragments (3 gates x 16 k-chunks of its K-half),
// f32 -> f16. j = this lane's B row; one-time cost (lives in AGPRs).
__device__ __forceinline__ void load_weights(f16x8 (&wB)[48], const float* __restrict__ W,
                                             int j, int kh, int kg) {
#pragma unroll
    for (int g = 0; g < 3; ++g)
#pragma unroll
        for (int i = 0; i < 16; ++i) {
            const float* p = W + (((size_t)g << 10) + j) * 1024 + (kh << 9) + (i << 5) + (kg << 3);
            float4 u = *(const float4*)p;
            float4 v = *(const float4*)(p + 4);
            f16x8 o;
            o[0] = (_Float16)u.x; o[1] = (_Float16)u.y; o[2] = (_Float16)u.z; o[3] = (_Float16)u.w;
            o[4] = (_Float16)v.x; o[5] = (_Float16)v.y; o[6] = (_Float16)v.z; o[7] = (_Float16)v.w;
            wB[g * 16 + i] = o;
        }
}

// ---- publish + sync tail ----
// wave0: 128 coalesced 16B scoped stores of hout -> hn slice, vmcnt(0) drain,
//        tid0 stores tag = gcur+1.
// wave2 lanes 0..15: poll all 16 group tags >= gcur+1 (overlaps wave0 drain).
// __syncthreads joins. Monotone tags, no reset race.
#define PUBLISH_SYNC(hn_expr, EXTRA_STORES)                                              \
    do {                                                                                 \
        if (tid < 64) {                                                                  \
            _Float16* hn_ = (hn_expr);                                                   \
            int ch0 = tid, ch1 = tid + 64;                                               \
            store_b128_coh(hn_ + ((size_t)(b0 + (ch0 >> 3)) << 10) + j0 + (ch0 & 7) * 8, \
                           *(const u32x4*)&hout[ch0 >> 3][(ch0 & 7) * 8]);               \
            store_b128_coh(hn_ + ((size_t)(b0 + (ch1 >> 3)) << 10) + j0 + (ch1 & 7) * 8, \
                           *(const u32x4*)&hout[ch1 >> 3][(ch1 & 7) * 8]);               \
        }                                                                                \
        EXTRA_STORES                                                                     \
        if (tid >= 128 && tid < 144) {                                                   \
            unsigned tgt = gcur + 1;                                                     \
            while (__hip_atomic_load(&tags[(bt * 16 + (tid - 128)) * 32],                \
                                     __ATOMIC_RELAXED, __HIP_MEMORY_SCOPE_AGENT) < tgt)  \
                __builtin_amdgcn_s_sleep(1);                                             \
        }                                                                                \
        if (tid < 64) {                                                                  \
            asm volatile("s_waitcnt vmcnt(0)" ::: "memory");                             \
            if (tid == 0)                                                                \
                __hip_atomic_store(&tags[(bt * 16 + jt) * 32], gcur + 1,                 \
                                   __ATOMIC_RELAXED, __HIP_MEMORY_SCOPE_AGENT);          \
        }                                                                                \
        __syncthreads();                                                                 \
        ++gcur;                                                                          \
    } while (0)

// One GRU phase: T steps. Weights in wB (AGPRs), h f32 master in hreg.
// h16 full-matrix [B][H] ping-pong: step t reads buf[t&1], writes buf[(t+1)&1].
template <bool DEC>
__device__ __forceinline__ void run_phase(
    int b0, int j0, int bt, int jt, int j, int np, int kh, int kg, int r16,
    int tid, int lane,
    const f16x8 (&wB)[48], float (&hreg)[4],
    _Float16* __restrict__ h16A, _Float16* __restrict__ h16B,
    const float* __restrict__ Wih, const float* __restrict__ bih,
    const float* __restrict__ bhh,
    const float* __restrict__ input, const float* __restrict__ Wout, float bout_v,
    float* __restrict__ xpart, float* __restrict__ outp,
    unsigned* tags, unsigned& gcur,
    char* Als, f32x4 (*red)[3][64], _Float16 (*hout)[64], float* xv_s, float (*xnp)[16])
{
    const float wi_r = Wih[j], wi_z = Wih[H + j], wi_n = Wih[2 * H + j];
    const float bi_r = bih[j], bi_z = bih[H + j], bi_n = bih[2 * H + j];
    const float bh_r = bhh[j], bh_z = bhh[H + j], bh_n = bhh[2 * H + j];
    const float wo = DEC ? Wout[j] : 0.f;
    const int kc = tid & 127, rb = tid >> 7;

    for (int t = 0; t < T; ++t) {
        const _Float16* hp = (t & 1) ? h16B : h16A;
        _Float16* hn = (t & 1) ? h16A : h16B;

        // ---- stage loads (freshness guaranteed by previous step's poll) ----
        u32x4 tmp[4];
#pragma unroll
        for (int i = 0; i < 4; ++i) {
            int row = i * 4 + rb;
            tmp[i] = load_b16_coh(hp + ((size_t)(b0 + row) << 10) + (kc << 3));
        }
        float xg = 0.f;
        if (DEC && t > 0 && tid < 16) {
            const float* xp = xpart + ((t - 1) & 1) * 4096 + (size_t)(b0 + tid) * 16;
#pragma unroll
            for (int q = 0; q < 16; ++q) xg += loadf_coh(xp + q);
            xg += bout_v;
        }
        asm volatile("s_waitcnt vmcnt(0)" ::: "memory");
        if (DEC && tid < 16) {
            float xv = (t > 0) ? xg : 0.f;
            xv_s[tid] = xv;
            if (t > 0 && jt == 0) outp[(size_t)(b0 + tid) * T + (t - 1)] = xv;
        }
#pragma unroll
        for (int i = 0; i < 4; ++i) {
            int row = i * 4 + rb;
            *(u32x4*)(Als + row * 2048 + ((kc << 4) ^ ((row & 7) << 4))) = tmp[i];
        }
        __syncthreads();

        // ---- MFMA: 3 gates x K-half ----
        f32x4 aR = {0.f, 0.f, 0.f, 0.f}, aZ = {0.f, 0.f, 0.f, 0.f}, aN = {0.f, 0.f, 0.f, 0.f};
#pragma unroll
        for (int i = 0; i < 16; ++i) {
            int kb = (kh << 10) + (i << 6) + (kg << 4);
            f16x8 a = *(const f16x8*)(Als + (r16 << 11) + (kb ^ ((r16 & 7) << 4)));
            aR = __builtin_amdgcn_mfma_f32_16x16x32_f16(a, wB[i], aR, 0, 0, 0);
            aZ = __builtin_amdgcn_mfma_f32_16x16x32_f16(a, wB[16 + i], aZ, 0, 0, 0);
            aN = __builtin_amdgcn_mfma_f32_16x16x32_f16(a, wB[32 + i], aN, 0, 0, 0);
        }
        if (kh == 1) {
            red[np][0][lane] = aR; red[np][1][lane] = aZ; red[np][2][lane] = aN;
        }
        __syncthreads();

        // ---- epilogue: K-reduce + GRU cell -> hout (LDS), xw -> xnp ----
        if (kh == 0) {
            f32x4 rR = red[np][0][lane], rZ = red[np][1][lane], rN = red[np][2][lane];
#pragma unroll
            for (int reg = 0; reg < 4; ++reg) {
                int row = kg * 4 + reg;
                int b = b0 + row;
                float xv = DEC ? xv_s[row] : input[(size_t)b * T + t];
                float r = sigmoidf_(xv * wi_r + bi_r + aR[reg] + rR[reg] + bh_r);
                float z = sigmoidf_(xv * wi_z + bi_z + aZ[reg] + rZ[reg] + bh_z);
                float n = tanhf_(xv * wi_n + bi_n + r * (aN[reg] + rN[reg] + bh_n));
                float hNew = (1.f - z) * n + z * hreg[reg];
                hreg[reg] = hNew;
                hout[row][np * 16 + r16] = (_Float16)hNew;
                if (DEC) {
                    float v = hNew * wo;
                    v += __shfl_xor(v, 1); v += __shfl_xor(v, 2);
                    v += __shfl_xor(v, 4); v += __shfl_xor(v, 8);
                    if (r16 == 0) xnp[np][row] = v;
                }
            }
        }
        __syncthreads();

        // ---- publish h_{t+1} (+ xpart), poll peers, join ----
        PUBLISH_SYNC(hn,
            if (DEC && tid < 16) {
                float s_ = xnp[0][tid] + xnp[1][tid] + xnp[2][tid] + xnp[3][tid];
                storef_coh(xpart + (t & 1) * 4096 + (size_t)(b0 + tid) * 16 + jt, s_);
            }
        );
    }
}

__global__ __launch_bounds__(512, 2) void gru_persistent(
    const float* __restrict__ input, const float* __restrict__ h_init,
    const float* __restrict__ Wih_e, const float* __restrict__ Whh_e,
    const float* __restrict__ bih_e, const float* __restrict__ bhh_e,
    const float* __restrict__ Wenc, const float* __restrict__ benc,
    const float* __restrict__ Wdec, const float* __restrict__ bdec,
    const float* __restrict__ Wih_d, const float* __restrict__ Whh_d,
    const float* __restrict__ bih_d, const float* __restrict__ bhh_d,
    const float* __restrict__ Wout, const float* __restrict__ boutp,
    float* __restrict__ featOut, float* __restrict__ outp,
    _Float16* __restrict__ h16A, _Float16* __restrict__ h16B,
    float* __restrict__ xpart, float* __restrict__ fpart,
    unsigned* tags)
{
    __shared__ __align__(16) char Als[32768];
    __shared__ f32x4 red[4][3][64];
    __shared__ __align__(16) _Float16 hout[16][64];
    __shared__ float xv_s[16];
    __shared__ float xnp[4][16];
    __shared__ float fp_np[4][16][3];
    __shared__ float feats[16][3];

    const int tid = threadIdx.x;
    const int lane = tid & 63;
    const int wv = tid >> 6;     // 0..7
    const int kh = wv & 1;       // K-half
    const int np = wv >> 1;      // n-quadrant 0..3
    const int kg = lane >> 4;    // 0..3
    const int r16 = lane & 15;
    const int bid = blockIdx.x;
    const int bt = bid & 15, jt = bid >> 4;   // group = {bt, bt+16, ...}
    const int b0 = bt * 16, j0 = jt * 64;
    const int j = j0 + np * 16 + r16;
    const float bout_v = boutp[0];
    unsigned gcur = 0;

    f16x8 wB[48];
    float hreg[4] = {0.f, 0.f, 0.f, 0.f};

    // ---- init: hreg + publish h_init slice to h16A (par0) ----
    if (kh == 0) {
#pragma unroll
        for (int reg = 0; reg < 4; ++reg) {
            int row = kg * 4 + reg;
            float v = h_init[((size_t)(b0 + row) << 10) + j];
            hreg[reg] = v;
            hout[row][np * 16 + r16] = (_Float16)v;
        }
    }
    __syncthreads();
    PUBLISH_SYNC(h16A, );
    load_weights(wB, Whh_e, j, kh, kg);

    // ---- encoder: 512 steps ----
    run_phase<false>(b0, j0, bt, jt, j, np, kh, kg, r16, tid, lane, wB, hreg,
                     h16A, h16B, Wih_e, bih_e, bhh_e, input, Wout, bout_v,
                     xpart, outp, tags, gcur, Als, red, hout, xv_s, xnp);

    // ---- bottleneck: features (16-way j reduction) + h0 ----
    {
        float we0 = Wenc[j], we1 = Wenc[H + j], we2 = Wenc[2 * H + j];
        if (kh == 0) {
#pragma unroll
            for (int reg = 0; reg < 4; ++reg) {
                float h = hreg[reg];
                float q0 = h * we0, q1 = h * we1, q2 = h * we2;
#pragma unroll
                for (int m = 1; m < 16; m <<= 1) {
                    q0 += __shfl_xor(q0, m);
                    q1 += __shfl_xor(q1, m);
                    q2 += __shfl_xor(q2, m);
                }
                if (r16 == 0) {
                    fp_np[np][kg * 4 + reg][0] = q0;
                    fp_np[np][kg * 4 + reg][1] = q1;
                    fp_np[np][kg * 4 + reg][2] = q2;
                }
            }
        }
        __syncthreads();
        if (tid < 48) {
            int bi = tid / 3, c = tid % 3;
            float s = fp_np[0][bi][c] + fp_np[1][bi][c] + fp_np[2][bi][c] + fp_np[3][bi][c];
            storef_coh(fpart + (size_t)(b0 + bi) * 48 + jt * 3 + c, s);
        }
        // sync (no h publish needed)
        if (tid >= 128 && tid < 144) {
            unsigned tgt = gcur + 1;
            while (__hip_atomic_load(&tags[(bt * 16 + (tid - 128)) * 32],
                                     __ATOMIC_RELAXED, __HIP_MEMORY_SCOPE_AGENT) < tgt)
                __builtin_amdgcn_s_sleep(1);
        }
        if (tid < 64) {
            asm volatile("s_waitcnt vmcnt(0)" ::: "memory");
            if (tid == 0)
                __hip_atomic_store(&tags[(bt * 16 + jt) * 32], gcur + 1,
                                   __ATOMIC_RELAXED, __HIP_MEMORY_SCOPE_AGENT);
        }
        __syncthreads();
        ++gcur;

        if (tid < 48) {
            int bi = tid / 3, c = tid % 3;
            float s = 0.f;
            const float* fp = fpart + (size_t)(b0 + bi) * 48 + c;
#pragma unroll
            for (int q = 0; q < 16; ++q) s += loadf_coh(fp + q * 3);
            float f = sigmoidf_(s + benc[c]);
            feats[bi][c] = f;
            if (jt == 0) featOut[(b0 + bi) * 3 + c] = f;
        }
        __syncthreads();

        // h0 = feats @ Wdec.T + bdec -> hreg + publish to h16A (decoder par0)
        if (kh == 0) {
#pragma unroll
            for (int reg = 0; reg < 4; ++reg) {
                int row = kg * 4 + reg;
                float v = feats[row][0] * Wdec[j * 3 + 0] + feats[row][1] * Wdec[j * 3 + 1] +
                          feats[row][2] * Wdec[j * 3 + 2] + bdec[j];
                hreg[reg] = v;
                hout[row][np * 16 + r16] = (_Float16)v;
            }
        }
        __syncthreads();
        PUBLISH_SYNC(h16A, );
        load_weights(wB, Whh_d, j, kh, kg);
    }

    // ---- decoder: 512 steps ----
    run_phase<true>(b0, j0, bt, jt, j, np, kh, kg, r16, tid, lane, wB, hreg,
                    h16A, h16B, Wih_d, bih_d, bhh_d, input, Wout, bout_v,
                    xpart, outp, tags, gcur, Als, red, hout, xv_s, xnp);

    // ---- final output column: x from step 511 (xpart slot 1, polled) ----
    if (jt == 0 && tid < 16) {
        const float* xp = xpart + 4096 + (size_t)(b0 + tid) * 16;
        float s = 0.f;
#pragma unroll
        for (int q = 0; q < 16; ++q) s += loadf_coh(xp + q);
        outp[(size_t)(b0 + tid) * T + (T - 1)] = s + bout_v;
    }
}

__global__ __launch_bounds__(256) void loss_partial(
    const float* __restrict__ input, const float* __restrict__ outp,
    float* __restrict__ partial)
{
    int idx = blockIdx.x * blockDim.x + threadIdx.x;
    float s = 0.f;
    for (int i = idx; i < B * T; i += gridDim.x * blockDim.x) {
        float d = input[i] - outp[i];
        s += d * d;
    }
#pragma unroll
    for (int off = 32; off; off >>= 1) s += __shfl_down(s, off);
    __shared__ float ws[4];
    if ((threadIdx.x & 63) == 0) ws[threadIdx.x >> 6] = s;
    __syncthreads();
    if (threadIdx.x == 0) partial[blockIdx.x] = ws[0] + ws[1] + ws[2] + ws[3];
}

__global__ __launch_bounds__(256) void loss_final(
    const float* __restrict__ partial, float* __restrict__ loss)
{
    int tid = threadIdx.x;
    float s = partial[tid];
#pragma unroll
    for (int off = 32; off; off >>= 1) s += __shfl_down(s, off);
    __shared__ float ws[4];
    if ((tid & 63) == 0) ws[tid >> 6] = s;
    __syncthreads();
    if (tid == 0) loss[0] = (ws[0] + ws[1] + ws[2] + ws[3]) * (1.0f / (float)(B * T));
}

extern "C" void kernel_launch(void* const* d_in, const int* in_sizes, int n_in,
                              void* d_out, int out_size, void* d_ws, size_t ws_size,
                              hipStream_t stream) {
    const float* input = (const float*)d_in[0];
    const float* h_init = (const float*)d_in[1];
    const float* Wih_e = (const float*)d_in[2];
    const float* Whh_e = (const float*)d_in[3];
    const float* bih_e = (const float*)d_in[4];
    const float* bhh_e = (const float*)d_in[5];
    const float* Wenc  = (const float*)d_in[6];
    const float* benc  = (const float*)d_in[7];
    const float* Wdec  = (const float*)d_in[8];
    const float* bdec  = (const float*)d_in[9];
    const float* Wih_d = (const float*)d_in[10];
    const float* Whh_d = (const float*)d_in[11];
    const float* bih_d = (const float*)d_in[12];
    const float* bhh_d = (const float*)d_in[13];
    const float* Wout  = (const float*)d_in[14];
    const float* bout  = (const float*)d_in[15];
    (void)in_sizes; (void)n_in; (void)out_size; (void)ws_size;

    float* out = (float*)d_out;
    float* lossp = out;                    // [1]
    float* feat = out + 1;                 // [B*3]
    float* outp = out + 1 + B * 3;         // [B*T]

    // ---- workspace layout ----
    char* ws = (char*)d_ws;
    _Float16* h16A = (_Float16*)ws;                  ws += (size_t)B * H * 2;
    _Float16* h16B = (_Float16*)ws;                  ws += (size_t)B * H * 2;
    float* xpart = (float*)ws;                       ws += 2 * 4096 * 4;   // [2][256][16]
    float* fpart = (float*)ws;                       ws += (size_t)B * 48 * 4;
    float* partial = (float*)ws;                     ws += 256 * 4;
    unsigned* tags = (unsigned*)ws;                  ws += 16 * 16 * 32 * 4;  // padded tag lines

    // tags must start at 0 every call (ws poisoned once, not restored)
    hipMemsetAsync(tags, 0, 16 * 16 * 32 * 4, stream);

    gru_persistent<<<dim3(NBLK), dim3(512), 0, stream>>>(
        input, h_init, Wih_e, Whh_e, bih_e, bhh_e, Wenc, benc, Wdec, bdec,
        Wih_d, Whh_d, bih_d, bhh_d, Wout, bout,
        feat, outp, h16A, h16B, xpart, fpart, tags);

    loss_partial<<<256, 256, 0, stream>>>(input, outp, partial);
    loss_final<<<1, 256, 0, stream>>>(partial, lossp);
}